// Round 4
// baseline (95.377 us; speedup 1.0000x reference)
//
#include <hip/hip_runtime.h>

typedef float  f32x4  __attribute__((ext_vector_type(4)));
typedef short  s16x8  __attribute__((ext_vector_type(8)));
typedef short  s16x4  __attribute__((ext_vector_type(4)));

#define NROWS (2048 * 128)
#define RPB 128          // rows per block (4 waves x 32)
#define HS 104           // h1/h2 LDS stride in shorts (208 B, 16B-aligned, odd dword)
#define EPSF 1e-8f

// fp32 -> bf16, round-to-nearest-even (proven in Round 3)
__device__ __forceinline__ unsigned short f2bf(float f) {
    unsigned int u = __float_as_uint(f);
    u += 0x7fffu + ((u >> 16) & 1u);
    return (unsigned short)(u >> 16);
}

// ---------------------------------------------------------------------------
// Pre-kernel: repack weights to bf16 MFMA B-fragment order (unchanged from R3).
// B-frag (16x16x32): lane l holds B[k][col]: col=l&15, k=(l>>4)*8+j
// ---------------------------------------------------------------------------
__global__ void repack(const float* __restrict__ W1, const float* __restrict__ b1,
                       const float* __restrict__ W2, const float* __restrict__ b2,
                       const float* __restrict__ W3, const float* __restrict__ b3,
                       unsigned short* __restrict__ w1f, unsigned short* __restrict__ w2f,
                       unsigned short* __restrict__ w3f,
                       float* __restrict__ b1p, float* __restrict__ b2p,
                       float* __restrict__ b3p)
{
    const int b = blockIdx.x;
    const int l = threadIdx.x;      // 64 threads
    const int g = l >> 4, sl = l & 15;

    if (b < 24) {                   // W1: nt = b>>2, ks = b&3
        const int nt = b >> 2, ks = b & 3;
        const int o = nt * 16 + sl, kb = ks * 32 + g * 8;
        s16x8 v;
#pragma unroll
        for (int j = 0; j < 8; ++j) v[j] = (short)f2bf(W1[o * 128 + kb + j]);
        *(s16x8*)&w1f[b * 512 + l * 8] = v;
    } else if (b < 39) {            // W2 (out padded 72->80)
        const int f = b - 24, nt = f / 3, ks = f % 3;
        const int o = nt * 16 + sl, kb = ks * 32 + g * 8;
        s16x8 v;
#pragma unroll
        for (int j = 0; j < 8; ++j)
            v[j] = (short)((o < 72) ? f2bf(W2[o * 96 + kb + j]) : 0);
        *(s16x8*)&w2f[f * 512 + l * 8] = v;
    } else if (b < 51) {            // W3 (k padded 72->96)
        const int f = b - 39, nt = f / 3, ks = f % 3;
        const int o = nt * 16 + sl, kb = ks * 32 + g * 8;
        s16x8 v;
#pragma unroll
        for (int j = 0; j < 8; ++j)
            v[j] = (short)((kb + j < 72) ? f2bf(W3[o * 72 + kb + j]) : 0);
        *(s16x8*)&w3f[f * 512 + l * 8] = v;
    } else {                        // biases, zero-padded
        for (int i = l; i < 240; i += 64) {
            if (i < 96)       b1p[i] = b1[i];
            else if (i < 176) { int o = i - 96; b2p[o] = (o < 72) ? b2[o] : 0.f; }
            else              b3p[i - 176] = b3[i - 176];
        }
    }
}

// ---------------------------------------------------------------------------
// Main. Per block: 4 waves x 32 rows. No x staging: each wave loads its
// A-frag fp32 data directly from global and converts in-register. h1/h2
// live in a single wave-PRIVATE LDS buffer (stride 104 shorts) -> no
// inter-layer barriers; only one barrier before the block reduction.
// A-frag: act[sample=l&15][k=(l>>4)*8+j].  D: sample=(l>>4)*4+r, out=l&15.
// ---------------------------------------------------------------------------
__global__ __launch_bounds__(256, 3)
void mlp_main(const float* __restrict__ x,
              const unsigned short* __restrict__ w1f,
              const unsigned short* __restrict__ w2f,
              const unsigned short* __restrict__ w3f,
              const float* __restrict__ b1p, const float* __restrict__ b2p,
              const float* __restrict__ b3p,
              float* __restrict__ acc /* [65]: s[64], uu */)
{
    __shared__ __align__(16) unsigned short act[4][2][16][HS]; // 26.6 KB, wave-private slices
    __shared__ float sred[4][64];
    __shared__ float uured[4];

    const int tid  = threadIdx.x;
    const int lane = tid & 63;
    const int wv   = tid >> 6;
    const int g    = lane >> 4;
    const int sl   = lane & 15;

    const float* xw = x + (size_t)(blockIdx.x * RPB + wv * 32) * 128;

    union Frag { s16x8 v; unsigned short u[8]; };

    // ---- layer-1 A-frags: direct global fp32 -> bf16 in registers ----
    Frag A1[2][4];
#pragma unroll
    for (int st = 0; st < 2; ++st)
#pragma unroll
        for (int ks = 0; ks < 4; ++ks) {
            const float* p = xw + (size_t)(st * 16 + sl) * 128 + ks * 32 + g * 8;
            const f32x4 u0 = *(const f32x4*)p;
            const f32x4 u1 = *(const f32x4*)(p + 4);
#pragma unroll
            for (int j = 0; j < 4; ++j) {
                A1[st][ks].u[j]     = f2bf(u0[j]);
                A1[st][ks].u[4 + j] = f2bf(u1[j]);
            }
        }

    // ================= layer 1: 128 -> 96 =================
    f32x4 D1[2][6];
#pragma unroll
    for (int nt = 0; nt < 6; ++nt) {
        const float bb = b1p[nt * 16 + sl];
        D1[0][nt] = (f32x4){bb, bb, bb, bb};
        D1[1][nt] = D1[0][nt];
    }
#pragma unroll
    for (int ks = 0; ks < 4; ++ks)
#pragma unroll
        for (int nt = 0; nt < 6; ++nt) {
            const s16x8 B = *(const s16x8*)&w1f[(nt * 4 + ks) * 512 + lane * 8];
            D1[0][nt] = __builtin_amdgcn_mfma_f32_16x16x32_bf16(A1[0][ks].v, B, D1[0][nt], 0, 0, 0);
            D1[1][nt] = __builtin_amdgcn_mfma_f32_16x16x32_bf16(A1[1][ks].v, B, D1[1][nt], 0, 0, 0);
        }

    // relu + write h1[sample][feat]  (wave-private; no barrier)
#pragma unroll
    for (int st = 0; st < 2; ++st)
#pragma unroll
        for (int nt = 0; nt < 6; ++nt)
#pragma unroll
            for (int r = 0; r < 4; ++r)
                act[wv][st][g * 4 + r][nt * 16 + sl] = f2bf(fmaxf(D1[st][nt][r], 0.f));

    // ---- layer-2 A-frags from LDS (b128), then reuse buffer for h2 ----
    Frag A2[2][3];
#pragma unroll
    for (int st = 0; st < 2; ++st)
#pragma unroll
        for (int ks = 0; ks < 3; ++ks)
            A2[st][ks].v = *(const s16x8*)&act[wv][st][sl][ks * 32 + g * 8];

    // zero h2 pad features 80..95 (h1 frags already in regs; same-wave order)
    {
        const s16x4 z = (s16x4){0, 0, 0, 0};
        *(s16x4*)&act[wv][0][sl][80 + g * 4] = z;
        *(s16x4*)&act[wv][1][sl][80 + g * 4] = z;
    }

    // ================= layer 2: 96 -> 72 (padded 80) =================
    f32x4 D2[2][5];
#pragma unroll
    for (int nt = 0; nt < 5; ++nt) {
        const float bb = b2p[nt * 16 + sl];
        D2[0][nt] = (f32x4){bb, bb, bb, bb};
        D2[1][nt] = D2[0][nt];
    }
#pragma unroll
    for (int ks = 0; ks < 3; ++ks)
#pragma unroll
        for (int nt = 0; nt < 5; ++nt) {
            const s16x8 B = *(const s16x8*)&w2f[(nt * 3 + ks) * 512 + lane * 8];
            D2[0][nt] = __builtin_amdgcn_mfma_f32_16x16x32_bf16(A2[0][ks].v, B, D2[0][nt], 0, 0, 0);
            D2[1][nt] = __builtin_amdgcn_mfma_f32_16x16x32_bf16(A2[1][ks].v, B, D2[1][nt], 0, 0, 0);
        }

    // relu + write h2 over the h1 region (feats 0..79; 80..95 already zero)
#pragma unroll
    for (int st = 0; st < 2; ++st)
#pragma unroll
        for (int nt = 0; nt < 5; ++nt)
#pragma unroll
            for (int r = 0; r < 4; ++r)
                act[wv][st][g * 4 + r][nt * 16 + sl] = f2bf(fmaxf(D2[st][nt][r], 0.f));

    // ---- layer-3 A-frags ----
    Frag A3[2][3];
#pragma unroll
    for (int st = 0; st < 2; ++st)
#pragma unroll
        for (int ks = 0; ks < 3; ++ks)
            A3[st][ks].v = *(const s16x8*)&act[wv][st][sl][ks * 32 + g * 8];

    // ================= layer 3: 72 (padded 96) -> 64 =================
    f32x4 D3[2][4];
#pragma unroll
    for (int nt = 0; nt < 4; ++nt) {
        const float bb = b3p[nt * 16 + sl];
        D3[0][nt] = (f32x4){bb, bb, bb, bb};
        D3[1][nt] = D3[0][nt];
    }
#pragma unroll
    for (int ks = 0; ks < 3; ++ks)
#pragma unroll
        for (int nt = 0; nt < 4; ++nt) {
            const s16x8 B = *(const s16x8*)&w3f[(nt * 3 + ks) * 512 + lane * 8];
            D3[0][nt] = __builtin_amdgcn_mfma_f32_16x16x32_bf16(A3[0][ks].v, B, D3[0][nt], 0, 0, 0);
            D3[1][nt] = __builtin_amdgcn_mfma_f32_16x16x32_bf16(A3[1][ks].v, B, D3[1][nt], 0, 0, 0);
        }

    // ============ epilogue: row norm + s / uu reduction (verified R3) ============
    float uu_part = 0.f;
    float s_part[4] = {0.f, 0.f, 0.f, 0.f};
#pragma unroll
    for (int st = 0; st < 2; ++st) {
        float ffr[4];
#pragma unroll
        for (int r = 0; r < 4; ++r) {
            float a = 0.f;
#pragma unroll
            for (int nt = 0; nt < 4; ++nt)
                a = fmaf(D3[st][nt][r], D3[st][nt][r], a);
            ffr[r] = a;
        }
#pragma unroll
        for (int r = 0; r < 4; ++r) {
            ffr[r] += __shfl_xor(ffr[r], 1, 64);
            ffr[r] += __shfl_xor(ffr[r], 2, 64);
            ffr[r] += __shfl_xor(ffr[r], 4, 64);
            ffr[r] += __shfl_xor(ffr[r], 8, 64);
        }
        float inv[4];
#pragma unroll
        for (int r = 0; r < 4; ++r) {
            inv[r] = 1.f / fmaxf(sqrtf(ffr[r]), EPSF);
            uu_part = fmaf(ffr[r] * inv[r], inv[r], uu_part);  // dup x16 over sl
        }
#pragma unroll
        for (int nt = 0; nt < 4; ++nt)
#pragma unroll
            for (int r = 0; r < 4; ++r)
                s_part[nt] = fmaf(D3[st][nt][r], inv[r], s_part[nt]);
    }
#pragma unroll
    for (int nt = 0; nt < 4; ++nt) {
        s_part[nt] += __shfl_xor(s_part[nt], 16, 64);
        s_part[nt] += __shfl_xor(s_part[nt], 32, 64);
    }
    uu_part += __shfl_xor(uu_part, 16, 64);
    uu_part += __shfl_xor(uu_part, 32, 64);

    if (g == 0) {
#pragma unroll
        for (int nt = 0; nt < 4; ++nt) sred[wv][nt * 16 + sl] = s_part[nt];
    }
    if (lane == 0) uured[wv] = uu_part * 0.0625f;
    __syncthreads();                               // the only barrier

    if (tid < 64) {
        const float t = sred[0][tid] + sred[1][tid] + sred[2][tid] + sred[3][tid];
        atomicAdd(&acc[tid], t);
    }
    if (tid == 0)
        atomicAdd(&acc[64], uured[0] + uured[1] + uured[2] + uured[3]);
}

__global__ void finalize_k(const float* __restrict__ acc, float* __restrict__ out)
{
    float s = acc[threadIdx.x];
    float d = s * s;
#pragma unroll
    for (int off = 32; off > 0; off >>= 1)
        d += __shfl_xor(d, off, 64);
    if (threadIdx.x == 0)
        out[0] = 0.5f * (d - acc[64]) / (float)NROWS;
}

extern "C" void kernel_launch(void* const* d_in, const int* in_sizes, int n_in,
                              void* d_out, int out_size, void* d_ws, size_t ws_size,
                              hipStream_t stream)
{
    const float* x  = (const float*)d_in[0];
    const float* W1 = (const float*)d_in[1];
    const float* b1 = (const float*)d_in[2];
    const float* W2 = (const float*)d_in[3];
    const float* b2 = (const float*)d_in[4];
    const float* W3 = (const float*)d_in[5];
    const float* b3 = (const float*)d_in[6];

    char* ws = (char*)d_ws;
    float*          acc = (float*)ws;                      // 1 KB
    unsigned short* w1f = (unsigned short*)(ws + 1024);    // 24576 B
    unsigned short* w2f = (unsigned short*)(ws + 25600);   // 15360 B
    unsigned short* w3f = (unsigned short*)(ws + 40960);   // 12288 B
    float*          b1p = (float*)(ws + 53248);
    float*          b2p = (float*)(ws + 53632);
    float*          b3p = (float*)(ws + 53952);

    hipMemsetAsync(acc, 0, 1024, stream);
    repack<<<52, 64, 0, stream>>>(W1, b1, W2, b2, W3, b3, w1f, w2f, w3f, b1p, b2p, b3p);
    mlp_main<<<NROWS / RPB, 256, 0, stream>>>(x, w1f, w2f, w3f, b1p, b2p, b3p, acc);
    finalize_k<<<1, 64, 0, stream>>>(acc, (float*)d_out);
}

// Round 5
// 69.469 us; speedup vs baseline: 1.3729x; 1.3729x over previous
//
#include <hip/hip_runtime.h>

typedef float  f32x4  __attribute__((ext_vector_type(4)));
typedef short  s16x8  __attribute__((ext_vector_type(8)));
typedef short  s16x4  __attribute__((ext_vector_type(4)));

#define NROWS (2048 * 128)
#define RPB 128          // rows per block-tile (4 waves x 32)
#define TILES 4          // row-tiles per block
#define HS 104           // act LDS stride in shorts
#define EPSF 1e-8f

union Frag { s16x8 v; unsigned short u[8]; };

// fp32 -> bf16 RTNE (verified R3/R4)
__device__ __forceinline__ unsigned short f2bf(float f) {
    unsigned int u = __float_as_uint(f);
    u += 0x7fffu + ((u >> 16) & 1u);
    return (unsigned short)(u >> 16);
}

// ---------------------------------------------------------------------------
// Pre-kernel: repack weights to bf16 MFMA B-fragment order (unchanged).
// Output layout in d_ws is CONTIGUOUS: w1f(24576 B) w2f(15360) w3f(12288)
// b1p(384) b2p(320) b3p(256) = 53184 B, staged to LDS by the main kernel.
// ---------------------------------------------------------------------------
__global__ void repack(const float* __restrict__ W1, const float* __restrict__ b1,
                       const float* __restrict__ W2, const float* __restrict__ b2,
                       const float* __restrict__ W3, const float* __restrict__ b3,
                       unsigned short* __restrict__ w1f, unsigned short* __restrict__ w2f,
                       unsigned short* __restrict__ w3f,
                       float* __restrict__ b1p, float* __restrict__ b2p,
                       float* __restrict__ b3p)
{
    const int b = blockIdx.x;
    const int l = threadIdx.x;      // 64 threads
    const int g = l >> 4, sl = l & 15;

    if (b < 24) {                   // W1: nt = b>>2, ks = b&3
        const int nt = b >> 2, ks = b & 3;
        const int o = nt * 16 + sl, kb = ks * 32 + g * 8;
        s16x8 v;
#pragma unroll
        for (int j = 0; j < 8; ++j) v[j] = (short)f2bf(W1[o * 128 + kb + j]);
        *(s16x8*)&w1f[b * 512 + l * 8] = v;
    } else if (b < 39) {            // W2 (out padded 72->80)
        const int f = b - 24, nt = f / 3, ks = f % 3;
        const int o = nt * 16 + sl, kb = ks * 32 + g * 8;
        s16x8 v;
#pragma unroll
        for (int j = 0; j < 8; ++j)
            v[j] = (short)((o < 72) ? f2bf(W2[o * 96 + kb + j]) : 0);
        *(s16x8*)&w2f[f * 512 + l * 8] = v;
    } else if (b < 51) {            // W3 (k padded 72->96)
        const int f = b - 39, nt = f / 3, ks = f % 3;
        const int o = nt * 16 + sl, kb = ks * 32 + g * 8;
        s16x8 v;
#pragma unroll
        for (int j = 0; j < 8; ++j)
            v[j] = (short)((kb + j < 72) ? f2bf(W3[o * 72 + kb + j]) : 0);
        *(s16x8*)&w3f[f * 512 + l * 8] = v;
    } else {                        // biases, zero-padded
        for (int i = l; i < 240; i += 64) {
            if (i < 96)       b1p[i] = b1[i];
            else if (i < 176) { int o = i - 96; b2p[o] = (o < 72) ? b2[o] : 0.f; }
            else              b3p[i - 176] = b3[i - 176];
        }
    }
}

// ---------------------------------------------------------------------------
// Main. 512 blocks x 256 thr; each block: stage 53.2 KB weights->LDS once,
// then 4 row-tiles of 128 rows. Per wave: 32 rows/tile, x prefetched one
// tile ahead into registers, B-frags from LDS (ds_read_b128), activations
// in wave-private LDS, no inter-layer barriers. s/uu accumulate across
// tiles in registers; one block reduction + atomics at the end.
// ---------------------------------------------------------------------------
__global__ __launch_bounds__(256, 2)
void mlp_main(const float* __restrict__ x,
              const f32x4* __restrict__ wsrc,   // 3324 x 16 B = weights+biases
              float* __restrict__ acc /* [65]: s[64], uu */)
{
    __shared__ __align__(16) unsigned char  wb[53184];           // w1|w2|w3|b1|b2|b3
    __shared__ __align__(16) unsigned short act[4][2][16][HS];   // 26.6 KB wave-private
    __shared__ float sred[4][64];
    __shared__ float uured[4];

    const unsigned short* w1L = (const unsigned short*)wb;   // 24 frags
    const unsigned short* w2L = w1L + 12288;                 // 15 frags
    const unsigned short* w3L = w1L + 19968;                 // 12 frags
    const float* b1L = (const float*)(wb + 52224);           // 96
    const float* b2L = b1L + 96;                             // 80
    const float* b3L = b1L + 176;                            // 64

    const int tid  = threadIdx.x;
    const int lane = tid & 63;
    const int wv   = tid >> 6;
    const int g    = lane >> 4;
    const int sl   = lane & 15;

    // lane-fixed part of the x address: row (st*16+sl), col (ks*32+g*8)
    auto loadx = [&](f32x4 (&xp)[16], int tile) {
        const float* xw = x + ((size_t)(blockIdx.x * TILES + tile) * RPB + wv * 32) * 128;
#pragma unroll
        for (int st = 0; st < 2; ++st)
#pragma unroll
            for (int ks = 0; ks < 4; ++ks) {
                const float* p = xw + (st * 16 + sl) * 128 + ks * 32 + g * 8;
                xp[st * 8 + ks * 2 + 0] = *(const f32x4*)p;
                xp[st * 8 + ks * 2 + 1] = *(const f32x4*)(p + 4);
            }
    };

    // ---- issue tile-0 x loads BEFORE weight staging (overlap) ----
    f32x4 xp[16];
    loadx(xp, 0);

    // ---- stage weights + biases to LDS (53184 B = 3324 f32x4) ----
    for (int i = tid; i < 3324; i += 256)
        ((f32x4*)wb)[i] = wsrc[i];
    __syncthreads();                      // weights visible to all waves

    float uu_part = 0.f;
    float s_part[4] = {0.f, 0.f, 0.f, 0.f};

    for (int t = 0; t < TILES; ++t) {
        // convert current tile's x to A-frags
        Frag A1[2][4];
#pragma unroll
        for (int st = 0; st < 2; ++st)
#pragma unroll
            for (int ks = 0; ks < 4; ++ks)
#pragma unroll
                for (int j = 0; j < 4; ++j) {
                    A1[st][ks].u[j]     = f2bf(xp[st * 8 + ks * 2 + 0][j]);
                    A1[st][ks].u[4 + j] = f2bf(xp[st * 8 + ks * 2 + 1][j]);
                }

        // prefetch next tile (independent of everything below)
        if (t + 1 < TILES) loadx(xp, t + 1);

        // ================= layer 1: 128 -> 96 =================
        f32x4 D1[2][6];
#pragma unroll
        for (int nt = 0; nt < 6; ++nt) {
            const float bb = b1L[nt * 16 + sl];
            D1[0][nt] = (f32x4){bb, bb, bb, bb};
            D1[1][nt] = D1[0][nt];
        }
#pragma unroll
        for (int ks = 0; ks < 4; ++ks)
#pragma unroll
            for (int nt = 0; nt < 6; ++nt) {
                const s16x8 B = *(const s16x8*)&w1L[(nt * 4 + ks) * 512 + lane * 8];
                D1[0][nt] = __builtin_amdgcn_mfma_f32_16x16x32_bf16(A1[0][ks].v, B, D1[0][nt], 0, 0, 0);
                D1[1][nt] = __builtin_amdgcn_mfma_f32_16x16x32_bf16(A1[1][ks].v, B, D1[1][nt], 0, 0, 0);
            }
#pragma unroll
        for (int st = 0; st < 2; ++st)
#pragma unroll
            for (int nt = 0; nt < 6; ++nt)
#pragma unroll
                for (int r = 0; r < 4; ++r)
                    act[wv][st][g * 4 + r][nt * 16 + sl] = f2bf(fmaxf(D1[st][nt][r], 0.f));

        // layer-2 A-frags (wave-private LDS; compiler inserts lgkmcnt)
        Frag A2[2][3];
#pragma unroll
        for (int st = 0; st < 2; ++st)
#pragma unroll
            for (int ks = 0; ks < 3; ++ks)
                A2[st][ks].v = *(const s16x8*)&act[wv][st][sl][ks * 32 + g * 8];

        // zero pad feats 80..95 (clobbered each tile by h1 writes)
        {
            const s16x4 z = (s16x4){0, 0, 0, 0};
            *(s16x4*)&act[wv][0][sl][80 + g * 4] = z;
            *(s16x4*)&act[wv][1][sl][80 + g * 4] = z;
        }

        // ================= layer 2: 96 -> 72 (pad 80) =================
        f32x4 D2[2][5];
#pragma unroll
        for (int nt = 0; nt < 5; ++nt) {
            const float bb = b2L[nt * 16 + sl];
            D2[0][nt] = (f32x4){bb, bb, bb, bb};
            D2[1][nt] = D2[0][nt];
        }
#pragma unroll
        for (int ks = 0; ks < 3; ++ks)
#pragma unroll
            for (int nt = 0; nt < 5; ++nt) {
                const s16x8 B = *(const s16x8*)&w2L[(nt * 3 + ks) * 512 + lane * 8];
                D2[0][nt] = __builtin_amdgcn_mfma_f32_16x16x32_bf16(A2[0][ks].v, B, D2[0][nt], 0, 0, 0);
                D2[1][nt] = __builtin_amdgcn_mfma_f32_16x16x32_bf16(A2[1][ks].v, B, D2[1][nt], 0, 0, 0);
            }
#pragma unroll
        for (int st = 0; st < 2; ++st)
#pragma unroll
            for (int nt = 0; nt < 5; ++nt)
#pragma unroll
                for (int r = 0; r < 4; ++r)
                    act[wv][st][g * 4 + r][nt * 16 + sl] = f2bf(fmaxf(D2[st][nt][r], 0.f));

        // layer-3 A-frags
        Frag A3[2][3];
#pragma unroll
        for (int st = 0; st < 2; ++st)
#pragma unroll
            for (int ks = 0; ks < 3; ++ks)
                A3[st][ks].v = *(const s16x8*)&act[wv][st][sl][ks * 32 + g * 8];

        // ================= layer 3: 72 (pad 96) -> 64 =================
        f32x4 D3[2][4];
#pragma unroll
        for (int nt = 0; nt < 4; ++nt) {
            const float bb = b3L[nt * 16 + sl];
            D3[0][nt] = (f32x4){bb, bb, bb, bb};
            D3[1][nt] = D3[0][nt];
        }
#pragma unroll
        for (int ks = 0; ks < 3; ++ks)
#pragma unroll
            for (int nt = 0; nt < 4; ++nt) {
                const s16x8 B = *(const s16x8*)&w3L[(nt * 3 + ks) * 512 + lane * 8];
                D3[0][nt] = __builtin_amdgcn_mfma_f32_16x16x32_bf16(A3[0][ks].v, B, D3[0][nt], 0, 0, 0);
                D3[1][nt] = __builtin_amdgcn_mfma_f32_16x16x32_bf16(A3[1][ks].v, B, D3[1][nt], 0, 0, 0);
            }

        // ===== epilogue: row norm; accumulate s/uu across tiles =====
#pragma unroll
        for (int st = 0; st < 2; ++st) {
            float ffr[4];
#pragma unroll
            for (int r = 0; r < 4; ++r) {
                float a = 0.f;
#pragma unroll
                for (int nt = 0; nt < 4; ++nt)
                    a = fmaf(D3[st][nt][r], D3[st][nt][r], a);
                ffr[r] = a;
            }
#pragma unroll
            for (int r = 0; r < 4; ++r) {
                ffr[r] += __shfl_xor(ffr[r], 1, 64);
                ffr[r] += __shfl_xor(ffr[r], 2, 64);
                ffr[r] += __shfl_xor(ffr[r], 4, 64);
                ffr[r] += __shfl_xor(ffr[r], 8, 64);
            }
            float inv[4];
#pragma unroll
            for (int r = 0; r < 4; ++r) {
                inv[r] = 1.f / fmaxf(sqrtf(ffr[r]), EPSF);
                uu_part = fmaf(ffr[r] * inv[r], inv[r], uu_part);  // dup x16 over sl
            }
#pragma unroll
            for (int nt = 0; nt < 4; ++nt)
#pragma unroll
                for (int r = 0; r < 4; ++r)
                    s_part[nt] = fmaf(D3[st][nt][r], inv[r], s_part[nt]);
        }
    }

    // cross-g reduction (once, after all tiles)
#pragma unroll
    for (int nt = 0; nt < 4; ++nt) {
        s_part[nt] += __shfl_xor(s_part[nt], 16, 64);
        s_part[nt] += __shfl_xor(s_part[nt], 32, 64);
    }
    uu_part += __shfl_xor(uu_part, 16, 64);
    uu_part += __shfl_xor(uu_part, 32, 64);

    if (g == 0) {
#pragma unroll
        for (int nt = 0; nt < 4; ++nt) sred[wv][nt * 16 + sl] = s_part[nt];
    }
    if (lane == 0) uured[wv] = uu_part * 0.0625f;
    __syncthreads();

    if (tid < 64) {
        const float t = sred[0][tid] + sred[1][tid] + sred[2][tid] + sred[3][tid];
        atomicAdd(&acc[tid], t);
    }
    if (tid == 0)
        atomicAdd(&acc[64], uured[0] + uured[1] + uured[2] + uured[3]);
}

__global__ void finalize_k(const float* __restrict__ acc, float* __restrict__ out)
{
    float s = acc[threadIdx.x];
    float d = s * s;
#pragma unroll
    for (int off = 32; off > 0; off >>= 1)
        d += __shfl_xor(d, off, 64);
    if (threadIdx.x == 0)
        out[0] = 0.5f * (d - acc[64]) / (float)NROWS;
}

extern "C" void kernel_launch(void* const* d_in, const int* in_sizes, int n_in,
                              void* d_out, int out_size, void* d_ws, size_t ws_size,
                              hipStream_t stream)
{
    const float* x  = (const float*)d_in[0];
    const float* W1 = (const float*)d_in[1];
    const float* b1 = (const float*)d_in[2];
    const float* W2 = (const float*)d_in[3];
    const float* b2 = (const float*)d_in[4];
    const float* W3 = (const float*)d_in[5];
    const float* b3 = (const float*)d_in[6];

    char* ws = (char*)d_ws;
    float*          acc = (float*)ws;                      // 1 KB
    unsigned short* w1f = (unsigned short*)(ws + 1024);    // 24576 B
    unsigned short* w2f = (unsigned short*)(ws + 25600);   // 15360 B
    unsigned short* w3f = (unsigned short*)(ws + 40960);   // 12288 B
    float*          b1p = (float*)(ws + 53248);            // 384 B
    float*          b2p = (float*)(ws + 53632);            // 320 B
    float*          b3p = (float*)(ws + 53952);            // 256 B  (ends 54208)

    hipMemsetAsync(acc, 0, 1024, stream);
    repack<<<52, 64, 0, stream>>>(W1, b1, W2, b2, W3, b3, w1f, w2f, w3f, b1p, b2p, b3p);
    mlp_main<<<NROWS / (RPB * TILES), 256, 0, stream>>>(
        x, (const f32x4*)(ws + 1024), acc);
    finalize_k<<<1, 64, 0, stream>>>(acc, (float*)d_out);
}